// Round 18
// baseline (116.198 us; speedup 1.0000x reference)
//
#include <hip/hip_runtime.h>
#include <cstdint>
#include <cstddef>

typedef _Float16 f16;
typedef _Float16 f16x4 __attribute__((ext_vector_type(4)));
typedef _Float16 f16x8 __attribute__((ext_vector_type(8)));
typedef float f32x4 __attribute__((ext_vector_type(4)));
typedef __fp16 h2 __attribute__((ext_vector_type(2)));

#define MFMA16(a, b, c) __builtin_amdgcn_mfma_f32_16x16x32_f16(a, b, c, 0, 0, 0)

static __device__ __forceinline__ void gld16(const void* g, void* l) {
  __builtin_amdgcn_global_load_lds(
      (const __attribute__((address_space(1))) void*)g,
      (__attribute__((address_space(3))) void*)l, 16, 0, 0);
}

static __device__ __forceinline__ h2 as_h2(uint32_t u) {
  union { uint32_t u; h2 h; } c; c.u = u; return c.h;
}

#define B_ 4
#define N_ 4096
#define C_ 512
#define H_ 8
#define D_ 64
#define BN_ROWS 16384
#define QKV_COLS 1536

// ---------------- kernel 1: fp32 -> fp16 convert (x, Wqkv, Wproj) ----------------
__global__ __launch_bounds__(256) void k_convert(
    const float* __restrict__ x, const float* __restrict__ wqkv,
    const float* __restrict__ wproj,
    f16* __restrict__ xh, f16* __restrict__ wqkvh, f16* __restrict__ wprojh)
{
  const int NX  = (BN_ROWS * C_) / 4;
  const int NW1 = (QKV_COLS * C_) / 4;
  const int NW2 = (C_ * C_) / 4;
  const int total = NX + NW1 + NW2;
  const int stride = gridDim.x * blockDim.x;
  for (int i = blockIdx.x * blockDim.x + threadIdx.x; i < total; i += stride) {
    const float4* s; f16x4* d; int j;
    if (i < NX)              { s = (const float4*)x;     d = (f16x4*)xh;     j = i; }
    else if (i < NX + NW1)   { s = (const float4*)wqkv;  d = (f16x4*)wqkvh;  j = i - NX; }
    else                     { s = (const float4*)wproj; d = (f16x4*)wprojh; j = i - NX - NW1; }
    float4 v = s[j];
    f16x4 o; o[0] = (f16)v.x; o[1] = (f16)v.y; o[2] = (f16)v.z; o[3] = (f16)v.w;
    d[j] = o;
  }
}

// ---------------- kernel 2: QKV GEMM — R2 schedule, 2 waves x 128x64 wave tile ----------------
// LDS-read accounting: R2's 4-wave 64x64 tiles read A-panel 2x + B-panel 2x =
// 64KB/block-K-step -> 2300cyc/CU at 3 blocks vs 480cyc MFMA -> 23% MfmaUtil.
// 128x64 wave tiles read A 1x + B 2x = 48KB (-25%). R13 "refuted" this with a
// spill-confounded test (launch_bounds(256,3) pin -> acc in scratch, VGPR=84,
// WRITE+37MB). Clean retest: 128 thr, 2 waves, NO min-waves pin, 32KB LDS.
__global__ __launch_bounds__(128) void k_qkv_gemm(
    const f16* __restrict__ X, const f16* __restrict__ W, f16* __restrict__ Out)
{
  __shared__ f16 As[128][64];
  __shared__ f16 Bs[128][64];
  int w = (blockIdx.x & 7) * 192 + (blockIdx.x >> 3);
  const int n0 = (w % 12) * 128;
  const int m0 = (w / 12) * 128;
  const int tid = threadIdx.x;
  const int wid = tid >> 6;              // 2 waves: col strip wid*64
  const int lane = tid & 63;
  const int lr = lane & 15, lg = lane >> 4;
  const int sr = lane >> 3;
  const int sslot = (lane & 7) ^ sr;
  f32x4 acc[8][4] = {};
  for (int kt = 0; kt < 512; kt += 64) {
#pragma unroll
    for (int i = 0; i < 8; ++i) {
      int chunk = wid * 8 + i;           // 16 chunks of 8 rows across 2 waves
      int row = chunk * 8 + sr;
      gld16(&X[(size_t)(m0 + row) * 512 + kt + sslot * 8], &As[chunk * 8][0]);
      gld16(&W[(size_t)(n0 + row) * 512 + kt + sslot * 8], &Bs[chunk * 8][0]);
    }
    __syncthreads();
#pragma unroll
    for (int kk = 0; kk < 2; ++kk) {
      f16x8 bf[4];
#pragma unroll
      for (int n = 0; n < 4; ++n)
        bf[n] = *(const f16x8*)&Bs[wid * 64 + n * 16 + lr][(((kk * 4 + lg) ^ (lr & 7)) * 8)];
#pragma unroll
      for (int m = 0; m < 8; ++m) {
        f16x8 af = *(const f16x8*)&As[m * 16 + lr][(((kk * 4 + lg) ^ (lr & 7)) * 8)];
#pragma unroll
        for (int n = 0; n < 4; ++n)
          acc[m][n] = MFMA16(bf[n], af, acc[m][n]);   // swapped operands
      }
    }
    __syncthreads();
  }
#pragma unroll
  for (int m = 0; m < 8; ++m)
#pragma unroll
    for (int n = 0; n < 4; ++n) {
      int row = m0 + m * 16 + lr;
      int col = n0 + wid * 64 + n * 16 + lg * 4;
      f16x4 o;
      bool relu = (col < 1024);
#pragma unroll
      for (int j = 0; j < 4; ++j) {
        float v = acc[m][n][j];
        if (relu) v = fmaxf(v, 0.f);
        o[j] = (f16)v;
      }
      *(f16x4*)&Out[(size_t)row * QKV_COLS + col] = o;
    }
}

// ---------------- kernel 3: partial K^T V — fdot2 ----------------
__global__ __launch_bounds__(256) void k_ktv(
    const f16* __restrict__ qkv, float* __restrict__ partial, float* __restrict__ pksum)
{
  __shared__ f16 ks[32][64];
  __shared__ f16 vs[32][64];
  const int bh = blockIdx.x, sp = blockIdx.y;
  const int b = bh >> 3, h = bh & 7;
  const int tid = threadIdx.x, wid = tid >> 6, lane = tid & 63;
  const int srow = lane >> 3, scol = (lane & 7) * 8;
  const int td = (wid << 2) | (lane >> 4);
  const int te = lane & 15;
  const uint32_t SEL_LO = 0x05040100u, SEL_HI = 0x07060302u;
  const h2 ones = {(__fp16)1.0f, (__fp16)1.0f};
  float acc[4][4] = {};
  float ksacc[4] = {0.f, 0.f, 0.f, 0.f};
  const size_t rowbase = (size_t)b * N_ + sp * 256;
  for (int t = 0; t < 8; ++t) {
    int nb = t * 32 + wid * 8 + srow;
    gld16(&qkv[(rowbase + nb) * QKV_COLS + 512 + h * 64 + scol], &ks[wid * 8][0]);
    gld16(&qkv[(rowbase + nb) * QKV_COLS + 1024 + h * 64 + scol], &vs[wid * 8][0]);
    __syncthreads();
#pragma unroll 4
    for (int n = 0; n < 32; n += 2) {
      uint2 ka = *(const uint2*)&ks[n][td * 4];
      uint2 kb = *(const uint2*)&ks[n + 1][td * 4];
      uint2 va = *(const uint2*)&vs[n][te * 4];
      uint2 vb = *(const uint2*)&vs[n + 1][te * 4];
      uint32_t kp[4], vp[4];
      kp[0] = __builtin_amdgcn_perm(kb.x, ka.x, SEL_LO);
      kp[1] = __builtin_amdgcn_perm(kb.x, ka.x, SEL_HI);
      kp[2] = __builtin_amdgcn_perm(kb.y, ka.y, SEL_LO);
      kp[3] = __builtin_amdgcn_perm(kb.y, ka.y, SEL_HI);
      vp[0] = __builtin_amdgcn_perm(vb.x, va.x, SEL_LO);
      vp[1] = __builtin_amdgcn_perm(vb.x, va.x, SEL_HI);
      vp[2] = __builtin_amdgcn_perm(vb.y, va.y, SEL_LO);
      vp[3] = __builtin_amdgcn_perm(vb.y, va.y, SEL_HI);
#pragma unroll
      for (int i = 0; i < 4; ++i)
#pragma unroll
        for (int j = 0; j < 4; ++j)
          acc[i][j] = __builtin_amdgcn_fdot2(as_h2(kp[i]), as_h2(vp[j]), acc[i][j], false);
      if (te == 0) {
#pragma unroll
        for (int i = 0; i < 4; ++i)
          ksacc[i] = __builtin_amdgcn_fdot2(as_h2(kp[i]), ones, ksacc[i], false);
      }
    }
    __syncthreads();
  }
  float* pp = partial + (size_t)(bh * 16 + sp) * 4096;
#pragma unroll
  for (int i = 0; i < 4; ++i)
#pragma unroll
    for (int j = 0; j < 4; ++j)
      pp[(td * 4 + i) * 64 + te * 4 + j] = acc[i][j];
  if (te == 0) {
    float* kp2 = pksum + (bh * 16 + sp) * 64;
#pragma unroll
    for (int i = 0; i < 4; ++i) kp2[td * 4 + i] = ksacc[i];
  }
}

// ---------------- kernel 4: reduce 16 partials ----------------
__global__ __launch_bounds__(256) void k_reduce(
    const float* __restrict__ partial, const float* __restrict__ pksum,
    float* __restrict__ attn_acc, float* __restrict__ ksum)
{
  const int bh = blockIdx.x, seg = blockIdx.y, tid = threadIdx.x;
  const int i = seg * 256 + tid;
  float s = 0.f;
#pragma unroll 8
  for (int sp = 0; sp < 16; ++sp) s += partial[(size_t)(bh * 16 + sp) * 4096 + i];
  attn_acc[bh * 4096 + i] = s;
  if (seg == 0 && tid < 64) {
    float t2 = 0.f;
#pragma unroll 8
    for (int sp = 0; sp < 16; ++sp) t2 += pksum[(bh * 16 + sp) * 64 + tid];
    ksum[bh * 64 + tid] = t2;
  }
}

// ---------------- kernel 5: FUSED attn1 + proj v4 — R17 exact ----------------
__global__ __launch_bounds__(512, 1) void k_attn_proj(
    const f16* __restrict__ qkv, const float* __restrict__ attn_acc,
    const float* __restrict__ ksum, const float* __restrict__ temp,
    const f16* __restrict__ Wp, const float* __restrict__ bias,
    float* __restrict__ attn1_out, float* __restrict__ Y)
{
  __shared__ f16 outs[8][64][64];
  __shared__ union {
    f16 attnT[8][64][64];
    f16 Bs[512][64];
  } u;
  __shared__ float ksum_s[512];
  __shared__ float bias_s[512];
  __shared__ float denom_s[8][64];

  const int bid = blockIdx.x;
  const int b = bid >> 6, sp = bid & 63;
  const size_t gr = (size_t)b * N_ + sp * 64;
  const int tid = threadIdx.x;
  const int wid = tid >> 6, lane = tid & 63;
  const int lr = lane & 15, lg = lane >> 4;
  const int sr = lane >> 3, sslot = (lane & 7) ^ sr;

  ksum_s[tid] = ksum[b * 512 + tid];   // wave-private: tid = wid*64+lane
  bias_s[tid] = bias[tid];             // wave-private likewise

#define STAGEPB(kc_)                                                          \
  do {                                                                        \
    _Pragma("unroll")                                                         \
    for (int rd = 0; rd < 8; ++rd)                                            \
      gld16(&Wp[(size_t)(wid * 64 + rd * 8 + sr) * 512 + (kc_) * 64 + sslot * 8], \
            &u.Bs[wid * 64 + rd * 8][0]);                                     \
  } while (0)

  // ================= Phase A: wave-per-head, one pass =================
  {
    const int h = wid;
    const float tsc = temp[h];
#pragma unroll
    for (int rr = 0; rr < 8; ++rr)
      gld16(&qkv[(gr + rr * 8 + sr) * QKV_COLS + h * 64 + sslot * 8],
            &outs[h][rr * 8][0]);
#pragma unroll
    for (int dc = 0; dc < 4; ++dc) {
      float vals[16];
#pragma unroll
      for (int x = 0; x < 16; ++x)
        vals[x] = attn_acc[(size_t)(b * 8 + h) * 4096 + (dc * 16 + x) * 64 + lane] * tsc;
#pragma unroll
      for (int half = 0; half < 2; ++half) {
        int slot = (dc * 2 + half) ^ (lane & 7);
        f16x8 pk;
#pragma unroll
        for (int j = 0; j < 8; ++j) pk[j] = (f16)vals[half * 8 + j];
        *(f16x8*)&u.attnT[h][lane][slot * 8] = pk;
      }
    }
    asm volatile("s_waitcnt vmcnt(0)" ::: "memory");
    {
      const int r = lane;
      float dot = 0.f;
#pragma unroll
      for (int c = 0; c < 8; ++c) {
        f16x8 qv = *(const f16x8*)&outs[h][r][((c ^ (r & 7)) * 8)];
#pragma unroll
        for (int j = 0; j < 8; ++j) dot += (float)qv[j] * ksum_s[h * 64 + c * 8 + j];
      }
      denom_s[h][r] = fmaxf(dot, 100.f);
    }
    f16x8 af[2][4], bf[4][2];
#pragma unroll
    for (int kk = 0; kk < 2; ++kk)
#pragma unroll
      for (int m = 0; m < 4; ++m)
        af[kk][m] = *(const f16x8*)&outs[h][m * 16 + lr][(((kk * 4 + lg) ^ (lr & 7)) * 8)];
#pragma unroll
    for (int et = 0; et < 4; ++et)
#pragma unroll
      for (int kk = 0; kk < 2; ++kk)
        bf[et][kk] = *(const f16x8*)&u.attnT[h][et * 16 + lr][(((kk * 4 + lg) ^ (lr & 7)) * 8)];
    asm volatile("s_waitcnt lgkmcnt(0)" ::: "memory");
    __builtin_amdgcn_sched_barrier(0);
    STAGEPB(0);
    f32x4 acc1[4][4] = {};
    __builtin_amdgcn_s_setprio(1);
#pragma unroll
    for (int kk = 0; kk < 2; ++kk)
#pragma unroll
      for (int m = 0; m < 4; ++m)
#pragma unroll
        for (int et = 0; et < 4; ++et)
          acc1[m][et] = MFMA16(bf[et][kk], af[kk][m], acc1[m][et]);
    __builtin_amdgcn_s_setprio(0);
#pragma unroll
    for (int m = 0; m < 4; ++m) {
      const int rl = m * 16 + lr;
      const float dn = denom_s[h][rl];
#pragma unroll
      for (int et = 0; et < 4; ++et) {
        int e = et * 16 + lg * 4;
        float4 o;
        o.x = acc1[m][et][0]; o.y = acc1[m][et][1]; o.z = acc1[m][et][2]; o.w = acc1[m][et][3];
        *(float4*)&attn1_out[((size_t)(b * 8 + h) * N_ + sp * 64 + rl) * 64 + e] = o;
        f16x4 oh;
#pragma unroll
        for (int j = 0; j < 4; ++j) oh[j] = (f16)(acc1[m][et][j] / dn);
        *(f16x4*)((char*)&outs[h][rl][0] + (((e >> 3) ^ (rl & 7)) * 16) + (lg & 1) * 8) = oh;
      }
    }
  }
  asm volatile("s_waitcnt lgkmcnt(0)" ::: "memory");
  __builtin_amdgcn_s_barrier();
  asm volatile("" ::: "memory");

  // ================= Phase B: proj, wave-private strips, ZERO barriers =================
  f32x4 accP[4][4] = {};
#pragma unroll
  for (int kc = 0; kc < 8; ++kc) {
    asm volatile("s_waitcnt vmcnt(0)" ::: "memory");
    f16x8 bfp[2][4], afp[2][4];
#pragma unroll
    for (int kk = 0; kk < 2; ++kk) {
#pragma unroll
      for (int n = 0; n < 4; ++n)
        bfp[kk][n] = *(const f16x8*)&u.Bs[wid * 64 + n * 16 + lr][(((kk * 4 + lg) ^ (lr & 7)) * 8)];
#pragma unroll
      for (int m = 0; m < 4; ++m)
        afp[kk][m] = *(const f16x8*)&outs[kc][m * 16 + lr][(((kk * 4 + lg) ^ (lr & 7)) * 8)];
    }
    asm volatile("s_waitcnt lgkmcnt(0)" ::: "memory");
    __builtin_amdgcn_sched_barrier(0);
    if (kc < 7) STAGEPB(kc + 1);
    __builtin_amdgcn_s_setprio(1);
#pragma unroll
    for (int kk = 0; kk < 2; ++kk)
#pragma unroll
      for (int m = 0; m < 4; ++m)
#pragma unroll
        for (int n = 0; n < 4; ++n)
          accP[m][n] = MFMA16(bfp[kk][n], afp[kk][m], accP[m][n]);
    __builtin_amdgcn_s_setprio(0);
  }
#undef STAGEPB

#pragma unroll
  for (int m = 0; m < 4; ++m)
#pragma unroll
    for (int n = 0; n < 4; ++n) {
      size_t row = gr + m * 16 + lr;
      int col = wid * 64 + n * 16 + lg * 4;
      float4 o;
      o.x = accP[m][n][0] + bias_s[col + 0];
      o.y = accP[m][n][1] + bias_s[col + 1];
      o.z = accP[m][n][2] + bias_s[col + 2];
      o.w = accP[m][n][3] + bias_s[col + 3];
      *(float4*)&Y[row * C_ + col] = o;
    }
}

extern "C" void kernel_launch(void* const* d_in, const int* in_sizes, int n_in,
                              void* d_out, int out_size, void* d_ws, size_t ws_size,
                              hipStream_t stream)
{
  const float* x     = (const float*)d_in[0];
  const float* wqkv  = (const float*)d_in[1];
  const float* temp  = (const float*)d_in[2];
  const float* wproj = (const float*)d_in[3];
  const float* bproj = (const float*)d_in[4];
  float* y_out     = (float*)d_out;
  float* attn1_out = (float*)d_out + 8388608;

  char* ws = (char*)d_ws;
  f16*   xh       = (f16*)(ws);                   // 16 MB; reused as `partial` after QKV
  float* partial  = (float*)(ws);                 // aliases xh; 8 MB used
  f16*   wqkvh    = (f16*)(ws + 16777216);
  f16*   wprojh   = (f16*)(ws + 18350080);
  f16*   qkvh     = (f16*)(ws + 18874368);
  float* attn_acc = (float*)(ws + 69206016);
  float* ksum     = (float*)(ws + 69730304);
  float* pksum    = (float*)(ws + 69738496);

  hipLaunchKernelGGL(k_convert,   dim3(2048),   dim3(256), 0, stream, x, wqkv, wproj, xh, wqkvh, wprojh);
  // QKV: 128 m-tiles x 12 n-tiles = 1536 blocks, 128 thr (2 waves), 32KB LDS
  hipLaunchKernelGGL(k_qkv_gemm,  dim3(1536),   dim3(128), 0, stream, xh, wqkvh, qkvh);
  hipLaunchKernelGGL(k_ktv,       dim3(32, 16), dim3(256), 0, stream, qkvh, partial, pksum);
  hipLaunchKernelGGL(k_reduce,    dim3(32, 16), dim3(256), 0, stream, partial, pksum, attn_acc, ksum);
  hipLaunchKernelGGL(k_attn_proj, dim3(256),    dim3(512), 0, stream,
                     qkvh, attn_acc, ksum, temp, wprojh, bproj, attn1_out, y_out);
}

// Round 19
// 103.573 us; speedup vs baseline: 1.1219x; 1.1219x over previous
//
#include <hip/hip_runtime.h>
#include <cstdint>
#include <cstddef>

typedef _Float16 f16;
typedef _Float16 f16x4 __attribute__((ext_vector_type(4)));
typedef _Float16 f16x8 __attribute__((ext_vector_type(8)));
typedef float f32x4 __attribute__((ext_vector_type(4)));
typedef __fp16 h2 __attribute__((ext_vector_type(2)));

#define MFMA16(a, b, c) __builtin_amdgcn_mfma_f32_16x16x32_f16(a, b, c, 0, 0, 0)

static __device__ __forceinline__ void gld16(const void* g, void* l) {
  __builtin_amdgcn_global_load_lds(
      (const __attribute__((address_space(1))) void*)g,
      (__attribute__((address_space(3))) void*)l, 16, 0, 0);
}

static __device__ __forceinline__ h2 as_h2(uint32_t u) {
  union { uint32_t u; h2 h; } c; c.u = u; return c.h;
}

#define B_ 4
#define N_ 4096
#define C_ 512
#define H_ 8
#define D_ 64
#define BN_ROWS 16384
#define QKV_COLS 1536

// ---------------- kernel 1: fp32 -> fp16 convert (x, Wqkv, Wproj) ----------------
__global__ __launch_bounds__(256) void k_convert(
    const float* __restrict__ x, const float* __restrict__ wqkv,
    const float* __restrict__ wproj,
    f16* __restrict__ xh, f16* __restrict__ wqkvh, f16* __restrict__ wprojh)
{
  const int NX  = (BN_ROWS * C_) / 4;
  const int NW1 = (QKV_COLS * C_) / 4;
  const int NW2 = (C_ * C_) / 4;
  const int total = NX + NW1 + NW2;
  const int stride = gridDim.x * blockDim.x;
  for (int i = blockIdx.x * blockDim.x + threadIdx.x; i < total; i += stride) {
    const float4* s; f16x4* d; int j;
    if (i < NX)              { s = (const float4*)x;     d = (f16x4*)xh;     j = i; }
    else if (i < NX + NW1)   { s = (const float4*)wqkv;  d = (f16x4*)wqkvh;  j = i - NX; }
    else                     { s = (const float4*)wproj; d = (f16x4*)wprojh; j = i - NX - NW1; }
    float4 v = s[j];
    f16x4 o; o[0] = (f16)v.x; o[1] = (f16)v.y; o[2] = (f16)v.z; o[3] = (f16)v.w;
    d[j] = o;
  }
}

// ---------------- kernel 2: QKV GEMM — R2 exact (41.5us proven; FROZEN) ----------------
__global__ __launch_bounds__(256) void k_qkv_gemm(
    const f16* __restrict__ X, const f16* __restrict__ W, f16* __restrict__ Out)
{
  __shared__ f16 As[128][64];
  __shared__ f16 Bs[128][64];
  int w = (blockIdx.x & 7) * 192 + (blockIdx.x >> 3);
  const int n0 = (w % 12) * 128;
  const int m0 = (w / 12) * 128;
  const int tid = threadIdx.x;
  const int wid = tid >> 6;
  const int lane = tid & 63;
  const int lr = lane & 15, lg = lane >> 4;
  const int sr = lane >> 3;
  const int sslot = (lane & 7) ^ sr;
  const int wr = (wid >> 1) * 64, wc = (wid & 1) * 64;
  f32x4 acc[4][4] = {};
  for (int kt = 0; kt < 512; kt += 64) {
#pragma unroll
    for (int i = 0; i < 4; ++i) {
      int chunk = wid * 4 + i;
      int row = chunk * 8 + sr;
      gld16(&X[(size_t)(m0 + row) * 512 + kt + sslot * 8], &As[chunk * 8][0]);
      gld16(&W[(size_t)(n0 + row) * 512 + kt + sslot * 8], &Bs[chunk * 8][0]);
    }
    __syncthreads();
#pragma unroll
    for (int kk = 0; kk < 2; ++kk) {
      f16x8 af[4], bf[4];
#pragma unroll
      for (int m = 0; m < 4; ++m)
        af[m] = *(const f16x8*)&As[wr + m * 16 + lr][(((kk * 4 + lg) ^ (lr & 7)) * 8)];
#pragma unroll
      for (int n = 0; n < 4; ++n)
        bf[n] = *(const f16x8*)&Bs[wc + n * 16 + lr][(((kk * 4 + lg) ^ (lr & 7)) * 8)];
#pragma unroll
      for (int m = 0; m < 4; ++m)
#pragma unroll
        for (int n = 0; n < 4; ++n)
          acc[m][n] = MFMA16(bf[n], af[m], acc[m][n]);
    }
    __syncthreads();
  }
#pragma unroll
  for (int m = 0; m < 4; ++m)
#pragma unroll
    for (int n = 0; n < 4; ++n) {
      int row = m0 + wr + m * 16 + lr;
      int col = n0 + wc + n * 16 + lg * 4;
      f16x4 o;
      bool relu = (col < 1024);
#pragma unroll
      for (int j = 0; j < 4; ++j) {
        float v = acc[m][n][j];
        if (relu) v = fmaxf(v, 0.f);
        o[j] = (f16)v;
      }
      *(f16x4*)&Out[(size_t)row * QKV_COLS + col] = o;
    }
}

// ---------------- kernel 3: partial K^T V — fdot2 ----------------
__global__ __launch_bounds__(256) void k_ktv(
    const f16* __restrict__ qkv, float* __restrict__ partial, float* __restrict__ pksum)
{
  __shared__ f16 ks[32][64];
  __shared__ f16 vs[32][64];
  const int bh = blockIdx.x, sp = blockIdx.y;
  const int b = bh >> 3, h = bh & 7;
  const int tid = threadIdx.x, wid = tid >> 6, lane = tid & 63;
  const int srow = lane >> 3, scol = (lane & 7) * 8;
  const int td = (wid << 2) | (lane >> 4);
  const int te = lane & 15;
  const uint32_t SEL_LO = 0x05040100u, SEL_HI = 0x07060302u;
  const h2 ones = {(__fp16)1.0f, (__fp16)1.0f};
  float acc[4][4] = {};
  float ksacc[4] = {0.f, 0.f, 0.f, 0.f};
  const size_t rowbase = (size_t)b * N_ + sp * 256;
  for (int t = 0; t < 8; ++t) {
    int nb = t * 32 + wid * 8 + srow;
    gld16(&qkv[(rowbase + nb) * QKV_COLS + 512 + h * 64 + scol], &ks[wid * 8][0]);
    gld16(&qkv[(rowbase + nb) * QKV_COLS + 1024 + h * 64 + scol], &vs[wid * 8][0]);
    __syncthreads();
#pragma unroll 4
    for (int n = 0; n < 32; n += 2) {
      uint2 ka = *(const uint2*)&ks[n][td * 4];
      uint2 kb = *(const uint2*)&ks[n + 1][td * 4];
      uint2 va = *(const uint2*)&vs[n][te * 4];
      uint2 vb = *(const uint2*)&vs[n + 1][te * 4];
      uint32_t kp[4], vp[4];
      kp[0] = __builtin_amdgcn_perm(kb.x, ka.x, SEL_LO);
      kp[1] = __builtin_amdgcn_perm(kb.x, ka.x, SEL_HI);
      kp[2] = __builtin_amdgcn_perm(kb.y, ka.y, SEL_LO);
      kp[3] = __builtin_amdgcn_perm(kb.y, ka.y, SEL_HI);
      vp[0] = __builtin_amdgcn_perm(vb.x, va.x, SEL_LO);
      vp[1] = __builtin_amdgcn_perm(vb.x, va.x, SEL_HI);
      vp[2] = __builtin_amdgcn_perm(vb.y, va.y, SEL_LO);
      vp[3] = __builtin_amdgcn_perm(vb.y, va.y, SEL_HI);
#pragma unroll
      for (int i = 0; i < 4; ++i)
#pragma unroll
        for (int j = 0; j < 4; ++j)
          acc[i][j] = __builtin_amdgcn_fdot2(as_h2(kp[i]), as_h2(vp[j]), acc[i][j], false);
      if (te == 0) {
#pragma unroll
        for (int i = 0; i < 4; ++i)
          ksacc[i] = __builtin_amdgcn_fdot2(as_h2(kp[i]), ones, ksacc[i], false);
      }
    }
    __syncthreads();
  }
  float* pp = partial + (size_t)(bh * 16 + sp) * 4096;
#pragma unroll
  for (int i = 0; i < 4; ++i)
#pragma unroll
    for (int j = 0; j < 4; ++j)
      pp[(td * 4 + i) * 64 + te * 4 + j] = acc[i][j];
  if (te == 0) {
    float* kp2 = pksum + (bh * 16 + sp) * 64;
#pragma unroll
    for (int i = 0; i < 4; ++i) kp2[td * 4 + i] = ksacc[i];
  }
}

// ---------------- kernel 4: reduce 16 partials ----------------
__global__ __launch_bounds__(256) void k_reduce(
    const float* __restrict__ partial, const float* __restrict__ pksum,
    float* __restrict__ attn_acc, float* __restrict__ ksum)
{
  const int bh = blockIdx.x, seg = blockIdx.y, tid = threadIdx.x;
  const int i = seg * 256 + tid;
  float s = 0.f;
#pragma unroll 8
  for (int sp = 0; sp < 16; ++sp) s += partial[(size_t)(bh * 16 + sp) * 4096 + i];
  attn_acc[bh * 4096 + i] = s;
  if (seg == 0 && tid < 64) {
    float t2 = 0.f;
#pragma unroll 8
    for (int sp = 0; sp < 16; ++sp) t2 += pksum[(bh * 16 + sp) * 64 + tid];
    ksum[bh * 64 + tid] = t2;
  }
}

// ---------------- kernel 5: FUSED attn1 + proj v4 — R15 exact (champion) ----------------
__global__ __launch_bounds__(512, 1) void k_attn_proj(
    const f16* __restrict__ qkv, const float* __restrict__ attn_acc,
    const float* __restrict__ ksum, const float* __restrict__ temp,
    const f16* __restrict__ Wp, const float* __restrict__ bias,
    float* __restrict__ attn1_out, float* __restrict__ Y)
{
  __shared__ f16 outs[8][64][64];
  __shared__ union {
    f16 attnT[8][64][64];
    f16 Bs[512][64];
  } u;
  __shared__ float ksum_s[512];
  __shared__ float bias_s[512];
  __shared__ float denom_s[8][64];

  const int bid = blockIdx.x;
  const int b = bid >> 6, sp = bid & 63;
  const size_t gr = (size_t)b * N_ + sp * 64;
  const int tid = threadIdx.x;
  const int wid = tid >> 6, lane = tid & 63;
  const int lr = lane & 15, lg = lane >> 4;
  const int sr = lane >> 3, sslot = (lane & 7) ^ sr;

  ksum_s[tid] = ksum[b * 512 + tid];
  bias_s[tid] = bias[tid];
  __syncthreads();

#define STAGEPB(kc_)                                                          \
  do {                                                                        \
    _Pragma("unroll")                                                         \
    for (int rd = 0; rd < 8; ++rd)                                            \
      gld16(&Wp[(size_t)(wid * 64 + rd * 8 + sr) * 512 + (kc_) * 64 + sslot * 8], \
            &u.Bs[wid * 64 + rd * 8][0]);                                     \
  } while (0)

  // ================= Phase A: wave-per-head, one pass =================
  {
    const int h = wid;
    const float tsc = temp[h];
#pragma unroll
    for (int rr = 0; rr < 8; ++rr)
      gld16(&qkv[(gr + rr * 8 + sr) * QKV_COLS + h * 64 + sslot * 8],
            &outs[h][rr * 8][0]);
#pragma unroll
    for (int dc = 0; dc < 4; ++dc) {
      float vals[16];
#pragma unroll
      for (int x = 0; x < 16; ++x)
        vals[x] = attn_acc[(size_t)(b * 8 + h) * 4096 + (dc * 16 + x) * 64 + lane] * tsc;
#pragma unroll
      for (int half = 0; half < 2; ++half) {
        int slot = (dc * 2 + half) ^ (lane & 7);
        f16x8 pk;
#pragma unroll
        for (int j = 0; j < 8; ++j) pk[j] = (f16)vals[half * 8 + j];
        *(f16x8*)&u.attnT[h][lane][slot * 8] = pk;
      }
    }
    asm volatile("s_waitcnt vmcnt(0)" ::: "memory");
    {
      const int r = lane;
      float dot = 0.f;
#pragma unroll
      for (int c = 0; c < 8; ++c) {
        f16x8 qv = *(const f16x8*)&outs[h][r][((c ^ (r & 7)) * 8)];
#pragma unroll
        for (int j = 0; j < 8; ++j) dot += (float)qv[j] * ksum_s[h * 64 + c * 8 + j];
      }
      denom_s[h][r] = fmaxf(dot, 100.f);
    }
    f16x8 af[2][4], bf[4][2];
#pragma unroll
    for (int kk = 0; kk < 2; ++kk)
#pragma unroll
      for (int m = 0; m < 4; ++m)
        af[kk][m] = *(const f16x8*)&outs[h][m * 16 + lr][(((kk * 4 + lg) ^ (lr & 7)) * 8)];
#pragma unroll
    for (int et = 0; et < 4; ++et)
#pragma unroll
      for (int kk = 0; kk < 2; ++kk)
        bf[et][kk] = *(const f16x8*)&u.attnT[h][et * 16 + lr][(((kk * 4 + lg) ^ (lr & 7)) * 8)];
    asm volatile("s_waitcnt lgkmcnt(0)" ::: "memory");
    __builtin_amdgcn_sched_barrier(0);
    STAGEPB(0);
    f32x4 acc1[4][4] = {};
    __builtin_amdgcn_s_setprio(1);
#pragma unroll
    for (int kk = 0; kk < 2; ++kk)
#pragma unroll
      for (int m = 0; m < 4; ++m)
#pragma unroll
        for (int et = 0; et < 4; ++et)
          acc1[m][et] = MFMA16(bf[et][kk], af[kk][m], acc1[m][et]);
    __builtin_amdgcn_s_setprio(0);
#pragma unroll
    for (int m = 0; m < 4; ++m) {
      const int rl = m * 16 + lr;
      const float dn = denom_s[h][rl];
#pragma unroll
      for (int et = 0; et < 4; ++et) {
        int e = et * 16 + lg * 4;
        float4 o;
        o.x = acc1[m][et][0]; o.y = acc1[m][et][1]; o.z = acc1[m][et][2]; o.w = acc1[m][et][3];
        *(float4*)&attn1_out[((size_t)(b * 8 + h) * N_ + sp * 64 + rl) * 64 + e] = o;
        f16x4 oh;
#pragma unroll
        for (int j = 0; j < 4; ++j) oh[j] = (f16)(acc1[m][et][j] / dn);
        *(f16x4*)((char*)&outs[h][rl][0] + (((e >> 3) ^ (rl & 7)) * 16) + (lg & 1) * 8) = oh;
      }
    }
  }
  asm volatile("s_waitcnt lgkmcnt(0)" ::: "memory");
  __builtin_amdgcn_s_barrier();
  asm volatile("" ::: "memory");

  // ================= Phase B: proj, wave-private strips, ZERO barriers =================
  f32x4 accP[4][4] = {};
#pragma unroll
  for (int kc = 0; kc < 8; ++kc) {
    asm volatile("s_waitcnt vmcnt(0)" ::: "memory");
    f16x8 bfp[2][4], afp[2][4];
#pragma unroll
    for (int kk = 0; kk < 2; ++kk) {
#pragma unroll
      for (int n = 0; n < 4; ++n)
        bfp[kk][n] = *(const f16x8*)&u.Bs[wid * 64 + n * 16 + lr][(((kk * 4 + lg) ^ (lr & 7)) * 8)];
#pragma unroll
      for (int m = 0; m < 4; ++m)
        afp[kk][m] = *(const f16x8*)&outs[kc][m * 16 + lr][(((kk * 4 + lg) ^ (lr & 7)) * 8)];
    }
    asm volatile("s_waitcnt lgkmcnt(0)" ::: "memory");
    __builtin_amdgcn_sched_barrier(0);
    if (kc < 7) STAGEPB(kc + 1);
    __builtin_amdgcn_s_setprio(1);
#pragma unroll
    for (int kk = 0; kk < 2; ++kk)
#pragma unroll
      for (int m = 0; m < 4; ++m)
#pragma unroll
        for (int n = 0; n < 4; ++n)
          accP[m][n] = MFMA16(bfp[kk][n], afp[kk][m], accP[m][n]);
    __builtin_amdgcn_s_setprio(0);
  }
#undef STAGEPB

#pragma unroll
  for (int m = 0; m < 4; ++m)
#pragma unroll
    for (int n = 0; n < 4; ++n) {
      size_t row = gr + m * 16 + lr;
      int col = wid * 64 + n * 16 + lg * 4;
      float4 o;
      o.x = accP[m][n][0] + bias_s[col + 0];
      o.y = accP[m][n][1] + bias_s[col + 1];
      o.z = accP[m][n][2] + bias_s[col + 2];
      o.w = accP[m][n][3] + bias_s[col + 3];
      *(float4*)&Y[row * C_ + col] = o;
    }
}

extern "C" void kernel_launch(void* const* d_in, const int* in_sizes, int n_in,
                              void* d_out, int out_size, void* d_ws, size_t ws_size,
                              hipStream_t stream)
{
  const float* x     = (const float*)d_in[0];
  const float* wqkv  = (const float*)d_in[1];
  const float* temp  = (const float*)d_in[2];
  const float* wproj = (const float*)d_in[3];
  const float* bproj = (const float*)d_in[4];
  float* y_out     = (float*)d_out;
  float* attn1_out = (float*)d_out + 8388608;

  char* ws = (char*)d_ws;
  f16*   xh       = (f16*)(ws);                   // 16 MB; reused as `partial` after QKV
  float* partial  = (float*)(ws);                 // aliases xh; 8 MB used
  f16*   wqkvh    = (f16*)(ws + 16777216);
  f16*   wprojh   = (f16*)(ws + 18350080);
  f16*   qkvh     = (f16*)(ws + 18874368);
  float* attn_acc = (float*)(ws + 69206016);
  float* ksum     = (float*)(ws + 69730304);
  float* pksum    = (float*)(ws + 69738496);

  hipLaunchKernelGGL(k_convert,   dim3(2048),   dim3(256), 0, stream, x, wqkv, wproj, xh, wqkvh, wprojh);
  hipLaunchKernelGGL(k_qkv_gemm,  dim3(1536),   dim3(256), 0, stream, xh, wqkvh, qkvh);
  hipLaunchKernelGGL(k_ktv,       dim3(32, 16), dim3(256), 0, stream, qkvh, partial, pksum);
  hipLaunchKernelGGL(k_reduce,    dim3(32, 16), dim3(256), 0, stream, partial, pksum, attn_acc, ksum);
  hipLaunchKernelGGL(k_attn_proj, dim3(256),    dim3(512), 0, stream,
                     qkvh, attn_acc, ksum, temp, wprojh, bproj, attn1_out, y_out);
}